// Round 3
// baseline (155.123 us; speedup 1.0000x reference)
//
#include <hip/hip_runtime.h>
#include <math.h>

// B=32, M=512, E=256, H=8, A=64. Rows R=B*M=16384, groups G=H*B=256, panel=32768.
// Pipeline: cast x->f16; fused W transpose-cast; fused QKV GEMM (global_load_lds +
// st_16x32-style XOR swizzle) + R GEMM; flash attention with in-LDS K/V transpose
// staging (swizzled, async-prefetch) and swapped-QK^T wave-parallel softmax;
// finalize head-mean + R + relu.

typedef _Float16 f16;
typedef _Float16 f16x2 __attribute__((ext_vector_type(2)));
typedef _Float16 f16x4 __attribute__((ext_vector_type(4)));
typedef _Float16 f16x8 __attribute__((ext_vector_type(8)));
typedef float    f32x4 __attribute__((ext_vector_type(4)));

typedef __attribute__((address_space(1))) const void* gas_t;
typedef __attribute__((address_space(3))) void* las_t;

__device__ __forceinline__ void gload16(const void* g, void* l) {
  __builtin_amdgcn_global_load_lds((gas_t)g, (las_t)l, 16, 0, 0);
}

// ---------------- cast fp32 -> f16 (x4) ----------------
__global__ __launch_bounds__(256) void k_cast(const float* __restrict__ in,
                                              f16* __restrict__ out, int n4) {
  int i = blockIdx.x * 256 + threadIdx.x;
  if (i < n4) {
    f32x4 v = reinterpret_cast<const f32x4*>(in)[i];
    f16x4 h;
    h[0] = (f16)v[0]; h[1] = (f16)v[1]; h[2] = (f16)v[2]; h[3] = (f16)v[3];
    reinterpret_cast<f16x4*>(out)[i] = h;
  }
}

// ---------------- fused weight transpose-cast: Wq|Wk|Wv -> Wt[1536][256], Wr -> Wrt[64][256] ----------------
__global__ __launch_bounds__(256) void k_transpose_w(const float* __restrict__ Wq,
                                                     const float* __restrict__ Wk,
                                                     const float* __restrict__ Wv,
                                                     const float* __restrict__ Wr,
                                                     f16* __restrict__ Wt,
                                                     f16* __restrict__ Wrt) {
  __shared__ f16 tile[64][68];
  int b = blockIdx.x;
  const float* src; f16* dst; int r0, c0, Cin;
  if (b < 96) {
    int ws = b >> 5, rem = b & 31;
    src = (ws == 0) ? Wq : (ws == 1) ? Wk : Wv;
    dst = Wt + ws * 512 * 256;
    Cin = 512; r0 = (rem >> 3) * 64; c0 = (rem & 7) * 64;
  } else {
    src = Wr; dst = Wrt; Cin = 64; r0 = (b - 96) * 64; c0 = 0;
  }
  int t = threadIdx.x;
#pragma unroll
  for (int u = 0; u < 8; ++u) {
    int e = u * 256 + t;
    int r = e >> 5, c = (e & 31) << 1;
    const float* p = src + (long)(r0 + r) * Cin + (c0 + c);
    f16x2 v; v[0] = (f16)p[0]; v[1] = (f16)p[1];
    *reinterpret_cast<f16x2*>(&tile[r][c]) = v;
  }
  __syncthreads();
#pragma unroll
  for (int u = 0; u < 16; ++u) {
    int f = u * 256 + t;
    int cc = f >> 6, rr = f & 63;
    dst[(long)(c0 + cc) * 256 + (r0 + rr)] = tile[rr][cc];
  }
}

// ---------------- f16 MFMA GEMM via global_load_lds + XOR swizzle ----------------
// C(16384 x N) = Xh(16384x256) @ Wt ([col][k]); logical LDS tile [row][64k],
// physical 16B-block pb = (col_blk) ^ (row&7); linear DMA dest, pre-swizzled source.
template <int BN, bool F32OUT>
__global__ __launch_bounds__(256, 3) void k_gemm(const f16* __restrict__ Xh,
                                                 const f16* __restrict__ Wt,
                                                 f16* __restrict__ outH,
                                                 float* __restrict__ outF, int N) {
  __shared__ f16 Ash[128 * 64];
  __shared__ f16 Bsh[BN * 64];
  constexpr int NT = BN / 32;
  int t = threadIdx.x;
  int w = t >> 6, l = t & 63;
  int lrow = l & 15, lg = l >> 4;
  int wm = w >> 1, wn = w & 1;
  int rb = blockIdx.x * 128, cb = blockIdx.y * BN;

  f32x4 acc[4][NT] = {};

  for (int kt = 0; kt < 4; ++kt) {
    int kb = kt * 64;
    __syncthreads();
#pragma unroll
    for (int i = 0; i < 4; ++i) {          // A: 1024 slots of 16B
      int slot = i * 256 + t;
      int row = slot >> 3, pblk = slot & 7;
      int blk = pblk ^ (row & 7);
      gload16(Xh + (long)(rb + row) * 256 + kb + blk * 8, Ash + slot * 8);
    }
#pragma unroll
    for (int i = 0; i < BN / 32; ++i) {    // B: BN*8 slots
      int slot = i * 256 + t;
      int row = slot >> 3, pblk = slot & 7;
      int blk = pblk ^ (row & 7);
      gload16(Wt + (long)(cb + row) * 256 + kb + blk * 8, Bsh + slot * 8);
    }
    __syncthreads();

    f16x8 af[4][2];
#pragma unroll
    for (int mi = 0; mi < 4; ++mi)
#pragma unroll
      for (int ks = 0; ks < 2; ++ks) {
        int r = 64 * wm + 16 * mi + lrow;
        af[mi][ks] = *reinterpret_cast<const f16x8*>(
            Ash + r * 64 + (((4 * ks + lg) ^ (lrow & 7)) * 8));
      }
#pragma unroll
    for (int nt = 0; nt < NT; ++nt) {
      int rB = (BN / 2) * wn + 16 * nt + lrow;
      f16x8 b0 = *reinterpret_cast<const f16x8*>(Bsh + rB * 64 + ((lg ^ (lrow & 7)) * 8));
      f16x8 b1 = *reinterpret_cast<const f16x8*>(Bsh + rB * 64 + (((4 + lg) ^ (lrow & 7)) * 8));
#pragma unroll
      for (int mi = 0; mi < 4; ++mi) {
        acc[mi][nt] = __builtin_amdgcn_mfma_f32_16x16x32_f16(af[mi][0], b0, acc[mi][nt], 0, 0, 0);
        acc[mi][nt] = __builtin_amdgcn_mfma_f32_16x16x32_f16(af[mi][1], b1, acc[mi][nt], 0, 0, 0);
      }
    }
  }
#pragma unroll
  for (int mi = 0; mi < 4; ++mi)
#pragma unroll
    for (int nt = 0; nt < NT; ++nt)
#pragma unroll
      for (int r = 0; r < 4; ++r) {
        int row = rb + 64 * wm + 16 * mi + 4 * (l >> 4) + r;
        int col = cb + (BN / 2) * wn + 16 * nt + lrow;
        float v = acc[mi][nt][r];
        if constexpr (F32OUT) {
          outF[(long)row * N + col] = v;
        } else {
          long idx = ((long)(col >> 9) << 23) + (long)row * 512 + (col & 511);
          outH[idx] = (f16)v;
        }
      }
}

// ---------------- flash attention: in-LDS K/V transpose staging + swapped QK^T ----------------
// Qh panels [m][a]; Kn panels [a][n] (natural); Vn panels [n][a] (natural); Of f16 panels [m][a].
// LDS: Ksh logical [n][a], Vsh logical [a][n], both with pb = (blk ^ (row>>3)-style) XOR swizzle.
__global__ __launch_bounds__(256, 4) void k_attn(const f16* __restrict__ Qh,
                                                 const f16* __restrict__ Kn,
                                                 const f16* __restrict__ Vn,
                                                 f16* __restrict__ Of) {
  __shared__ f16 Ksh[64 * 64];
  __shared__ f16 Vsh[64 * 64];
  __shared__ f16 Psh[4][32][72];
  int g = blockIdx.x, mb = blockIdx.y;
  int t = threadIdx.x, w = t >> 6, l = t & 63;
  int lrow = l & 15, lg = l >> 4, lk8 = lg * 8;
  long gp = (long)g * 32768;
  const f16* Qg = Qh + gp;
  const f16* Kg = Kn + gp;
  const f16* Vg = Vn + gp;
  f16* Og = Of + gp;
  int m0 = mb * 128 + w * 32;

  int sa = t >> 3;            // staging row-in-32 [0,32)
  int so = (t & 7) * 8;       // staging col offset

  // Q B-operand fragments from global (panel [m][a], a contiguous).
  f16x8 qf[2][2];
#pragma unroll
  for (int mi = 0; mi < 2; ++mi)
#pragma unroll
    for (int ks = 0; ks < 2; ++ks)
      qf[mi][ks] = *reinterpret_cast<const f16x8*>(Qg + (long)(m0 + 16 * mi + lrow) * 64 + 32 * ks + lk8);

  f32x4 accO[2][4] = {};
  float Mx[2] = {-INFINITY, -INFINITY}, Ls[2] = {0.f, 0.f};

  // stage chunk c's K (transpose [a][n]->[n][a]) and V ([n][a]->[a][n]) from regs into LDS
  auto write_stage = [&](f16x8 kr0, f16x8 kr1, f16x8 vr0, f16x8 vr1) {
#pragma unroll
    for (int s = 0; s < 2; ++s) {
      f16x8 kr = s ? kr1 : kr0;
      int a = s * 32 + sa;          // K source row (a), const a>>3 per wave
      int ab = a >> 3;
#pragma unroll
      for (int j = 0; j < 8; ++j) {
        int n = so + j;
        Ksh[n * 64 + ((ab ^ (n >> 3)) * 8) + (a & 7)] = kr[j];
      }
      f16x8 vr = s ? vr1 : vr0;
      int n2 = s * 32 + sa;         // V source row (key within chunk)
      int nb = n2 >> 3;
#pragma unroll
      for (int j = 0; j < 8; ++j) {
        int aa = so + j;
        Vsh[aa * 64 + ((nb ^ (aa >> 3)) * 8) + (n2 & 7)] = vr[j];
      }
    }
  };

  // prologue: load + stage chunk 0
  {
    f16x8 k0 = *reinterpret_cast<const f16x8*>(Kg + (long)(0 * 32 + sa) * 512 + so);
    f16x8 k1 = *reinterpret_cast<const f16x8*>(Kg + (long)(1 * 32 + sa) * 512 + so);
    f16x8 v0 = *reinterpret_cast<const f16x8*>(Vg + (long)(0 * 32 + sa) * 64 + so);
    f16x8 v1 = *reinterpret_cast<const f16x8*>(Vg + (long)(32 + sa) * 64 + so);
    write_stage(k0, k1, v0, v1);
  }
  __syncthreads();

  for (int c = 0; c < 8; ++c) {
    // async prefetch next chunk into registers (T14: issue early, write late)
    f16x8 kn0, kn1, vn0, vn1;
    if (c < 7) {
      int cn = c + 1;
      kn0 = *reinterpret_cast<const f16x8*>(Kg + (long)(0 * 32 + sa) * 512 + cn * 64 + so);
      kn1 = *reinterpret_cast<const f16x8*>(Kg + (long)(1 * 32 + sa) * 512 + cn * 64 + so);
      vn0 = *reinterpret_cast<const f16x8*>(Vg + (long)(cn * 64 + sa) * 64 + so);
      vn1 = *reinterpret_cast<const f16x8*>(Vg + (long)(cn * 64 + 32 + sa) * 64 + so);
    }

    // S^T = K · Q^T : A-frag = K[key][a] (swizzled read), B-frag = Q regs.
    // St[mi][nt]: reg r -> key = 16nt + 4lg + r, qrow = 16mi + lrow.
    f32x4 St[2][4] = {};
#pragma unroll
    for (int nt = 0; nt < 4; ++nt) {
      int n = 16 * nt + lrow, nb = n >> 3;
      f16x8 ka = *reinterpret_cast<const f16x8*>(Ksh + n * 64 + ((lg ^ nb) * 8));
      f16x8 kb = *reinterpret_cast<const f16x8*>(Ksh + n * 64 + (((4 + lg) ^ nb) * 8));
#pragma unroll
      for (int mi = 0; mi < 2; ++mi) {
        St[mi][nt] = __builtin_amdgcn_mfma_f32_16x16x32_f16(ka, qf[mi][0], St[mi][nt], 0, 0, 0);
        St[mi][nt] = __builtin_amdgcn_mfma_f32_16x16x32_f16(kb, qf[mi][1], St[mi][nt], 0, 0, 0);
      }
    }

    // wave-parallel online softmax (lane owns qrow = 16mi+lrow; keys split across lg)
    float scb[2][4];
#pragma unroll
    for (int mi = 0; mi < 2; ++mi) {
      float tm = St[mi][0][0];
#pragma unroll
      for (int nt = 0; nt < 4; ++nt)
#pragma unroll
        for (int r = 0; r < 4; ++r) tm = fmaxf(tm, St[mi][nt][r]);
      tm = fmaxf(tm, __shfl_xor(tm, 16));
      tm = fmaxf(tm, __shfl_xor(tm, 32));
      float nm = fmaxf(Mx[mi], tm);
      float sc = __expf(Mx[mi] - nm);
      Mx[mi] = nm;
      float ps = 0.f;
#pragma unroll
      for (int nt = 0; nt < 4; ++nt)
#pragma unroll
        for (int r = 0; r < 4; ++r) {
          float p = __expf(St[mi][nt][r] - nm);
          St[mi][nt][r] = p;
          ps += p;
        }
      ps += __shfl_xor(ps, 16);
      ps += __shfl_xor(ps, 32);
      Ls[mi] = Ls[mi] * sc + ps;
#pragma unroll
      for (int nt = 0; nt < 4; ++nt) {
        f16x4 p4;
        p4[0] = (f16)St[mi][nt][0]; p4[1] = (f16)St[mi][nt][1];
        p4[2] = (f16)St[mi][nt][2]; p4[3] = (f16)St[mi][nt][3];
        *reinterpret_cast<f16x4*>(&Psh[w][16 * mi + lrow][16 * nt + 4 * lg]) = p4;
      }
#pragma unroll
      for (int r = 0; r < 4; ++r) scb[mi][r] = __shfl(sc, 20 * lg + r);
    }
#pragma unroll
    for (int mi = 0; mi < 2; ++mi)
#pragma unroll
      for (int at = 0; at < 4; ++at)
#pragma unroll
        for (int r = 0; r < 4; ++r) accO[mi][at][r] *= scb[mi][r];

    // O += P · V : A-frag = P (own wave's Psh), B-frag = V^T[a][key] (swizzled read)
#pragma unroll
    for (int ks = 0; ks < 2; ++ks) {
      f16x8 pa[2];
#pragma unroll
      for (int mi = 0; mi < 2; ++mi)
        pa[mi] = *reinterpret_cast<const f16x8*>(&Psh[w][16 * mi + lrow][32 * ks + lk8]);
#pragma unroll
      for (int at = 0; at < 4; ++at) {
        int a = 16 * at + lrow, ab = a >> 3;
        f16x8 vb = *reinterpret_cast<const f16x8*>(Vsh + a * 64 + (((4 * ks + lg) ^ ab) * 8));
#pragma unroll
        for (int mi = 0; mi < 2; ++mi)
          accO[mi][at] = __builtin_amdgcn_mfma_f32_16x16x32_f16(pa[mi], vb, accO[mi][at], 0, 0, 0);
      }
    }

    __syncthreads();               // all waves done reading Ksh/Vsh
    if (c < 7) write_stage(kn0, kn1, vn0, vn1);
    __syncthreads();               // staged chunk visible
  }

  // epilogue: redistribute 1/L, normalize, store f16
#pragma unroll
  for (int mi = 0; mi < 2; ++mi) {
    float inv = 1.f / Ls[mi];
    float invb[4];
#pragma unroll
    for (int r = 0; r < 4; ++r) invb[r] = __shfl(inv, 20 * lg + r);
#pragma unroll
    for (int r = 0; r < 4; ++r) {
      int row = m0 + 16 * mi + 4 * lg + r;
#pragma unroll
      for (int at = 0; at < 4; ++at)
        Og[(long)row * 64 + 16 * at + lrow] = (f16)(accO[mi][at][r] * invb[r]);
    }
  }
}

// ---------------- finalize: head-mean + R + relu ----------------
__global__ __launch_bounds__(256) void k_finalize(const f16* __restrict__ Of,
                                                  const float* __restrict__ Rf,
                                                  float* __restrict__ out) {
  int i = blockIdx.x * 256 + threadIdx.x;
  f32x4 s = {};
#pragma unroll
  for (int h = 0; h < 8; ++h) {
    f16x4 o = reinterpret_cast<const f16x4*>(Of + (long)h * 1048576)[i];
#pragma unroll
    for (int j = 0; j < 4; ++j) s[j] += (float)o[j];
  }
  f32x4 r = reinterpret_cast<const f32x4*>(Rf)[i];
  f32x4 v = s * 0.125f + r;
#pragma unroll
  for (int j = 0; j < 4; ++j) v[j] = v[j] > 0.f ? v[j] : 0.f;
  reinterpret_cast<f32x4*>(out)[i] = v;
}

extern "C" void kernel_launch(void* const* d_in, const int* in_sizes, int n_in,
                              void* d_out, int out_size, void* d_ws, size_t ws_size,
                              hipStream_t stream) {
  const float* x  = (const float*)d_in[0];
  const float* Wq = (const float*)d_in[1];
  const float* Wk = (const float*)d_in[2];
  const float* Wv = (const float*)d_in[3];
  const float* Wr = (const float*)d_in[4];
  float* out = (float*)d_out;
  char* w = (char*)d_ws;

  // workspace layout (bytes), ~80.5 MiB total:
  f16*   Xh   = (f16*)(w + 0);           // 8,388,608
  f16*   Wt   = (f16*)(w + 8388608);     // 786,432
  f16*   Wrt  = (f16*)(w + 9175040);     // 32,768
  f16*   QKV  = (f16*)(w + 9207808);     // Qh|Kn|Vn, 3 x 16,777,216 (2^23 elems apart)
  f16*   Qh   = QKV;
  f16*   Kn   = (f16*)(w + 25985024);
  f16*   Vn   = (f16*)(w + 42762240);
  float* Rf   = (float*)(w + 59539456);  // 4,194,304
  f16*   Of   = (f16*)(w + 63733760);    // 16,777,216

  k_cast<<<4096, 256, 0, stream>>>(x, Xh, 1048576);
  k_transpose_w<<<100, 256, 0, stream>>>(Wq, Wk, Wv, Wr, Wt, Wrt);

  k_gemm<128, false><<<dim3(128, 12), 256, 0, stream>>>(Xh, Wt, QKV, nullptr, 512);
  k_gemm<64, true><<<dim3(128, 1), 256, 0, stream>>>(Xh, Wrt, nullptr, Rf, 64);

  k_attn<<<dim3(256, 4), 256, 0, stream>>>(Qh, Kn, Vn, Of);
  k_finalize<<<1024, 256, 0, stream>>>(Of, Rf, out);
}